// Round 2
// baseline (702.838 us; speedup 1.0000x reference)
//
#include <hip/hip_runtime.h>

#define NROWS   100000
#define DIM     592
#define NINV    128
#define NEQ     112
#define NCH     240
#define ROWS    32
#define BLK     256
#define HPAD    129

typedef float f32x4 __attribute__((ext_vector_type(4)));

__global__ __launch_bounds__(BLK, 2)
void evmlp_kernel(const float* __restrict__ ten,
                  const float* __restrict__ w1,
                  const float* __restrict__ g1,
                  const float* __restrict__ be1,
                  const float* __restrict__ w2,
                  const float* __restrict__ b2,
                  const float* __restrict__ g2,
                  const float* __restrict__ be2,
                  const float* __restrict__ w3,
                  const float* __restrict__ b3,
                  float* __restrict__ out)
{
    __shared__ __align__(16) float sXT[NCH * ROWS];   // 30720 B, [k][row] transposed
    __shared__ __align__(16) float sH [ROWS * HPAD];  // 16512 B, [row][col] padded

    const int t  = threadIdx.x;
    const int r0 = blockIdx.x * ROWS;

    // ---- preprocess A: invariant l=0 block -> sXT[k][r], k<128 ----
    for (int i = t; i < ROWS * NINV; i += BLK) {
        int r = i >> 7, k = i & 127;
        sXT[k * ROWS + r] = ten[(size_t)(r0 + r) * DIM + k];
    }
    // ---- preprocess B: equivariant channels -> x11 into sXT, x2 into out ----
    for (int i = t; i < ROWS * NEQ; i += BLK) {
        int r = i / NEQ, c = i - r * NEQ;
        int base, nc;
        if (c < 64)      { base = 3 * c;              nc = 3; }
        else if (c < 96) { base = 192 + 5 * (c - 64); nc = 5; }
        else             { base = 352 + 7 * (c - 96); nc = 7; }
        const float* p = ten + (size_t)(r0 + r) * DIM + NINV + base;
        float vals[7];
        float ss = 1.0f;                       // sumsq + 1
        for (int j = 0; j < nc; ++j) { float v = p[j]; vals[j] = v; ss += v * v; }
        float dv  = sqrtf(ss);
        float inv = 1.0f / dv;
        sXT[(NINV + c) * ROWS + r] = dv - 1.0f;
        float* po = out + (size_t)(r0 + r) * DIM + NINV + base;
        for (int j = 0; j < nc; ++j) po[j] = vals[j] * inv;
    }
    __syncthreads();

    const int cgrp = t & 31;       // columns 4*cgrp .. +3
    const int rgrp = t >> 5;       // rows    4*rgrp .. +3
    const int c0 = cgrp << 2;
    const int rr = rgrp << 2;

    float acc[4][4];

    // ---- GEMM1: h = x1 @ w1  (K=240), w1 streamed from global (L2-resident) ----
    #pragma unroll
    for (int i = 0; i < 4; ++i)
        #pragma unroll
        for (int j = 0; j < 4; ++j) acc[i][j] = 0.f;
    {
        const float* wp = w1 + c0;
        #pragma unroll 8
        for (int k = 0; k < NCH; ++k) {
            f32x4 wv = *(const f32x4*)(wp + k * NINV);
            f32x4 xv = *(const f32x4*)(sXT + k * ROWS + rr);
            #pragma unroll
            for (int i = 0; i < 4; ++i)
                #pragma unroll
                for (int j = 0; j < 4; ++j)
                    acc[i][j] += xv[i] * wv[j];
        }
    }
    #pragma unroll
    for (int i = 0; i < 4; ++i)
        #pragma unroll
        for (int j = 0; j < 4; ++j)
            sH[(rr + i) * HPAD + c0 + j] = acc[i][j];
    __syncthreads();

    // ---- LN1: each group of 8 lanes handles one row ----
    {
        const int row = t >> 3, j = t & 7;
        float vals[16];
        float s = 0.f, ss = 0.f;
        #pragma unroll
        for (int i = 0; i < 16; ++i) {
            float v = sH[row * HPAD + (i * 8 + j)];
            vals[i] = v; s += v; ss += v * v;
        }
        #pragma unroll
        for (int off = 1; off < 8; off <<= 1) {
            s  += __shfl_xor(s,  off);
            ss += __shfl_xor(ss, off);
        }
        float mu   = s * (1.f / 128.f);
        float var  = ss * (1.f / 128.f) - mu * mu;
        float rstd = rsqrtf(var + 1e-5f);
        #pragma unroll
        for (int i = 0; i < 16; ++i) {
            int c = i * 8 + j;
            sXT[c * ROWS + row] = (vals[i] - mu) * rstd * g1[c] + be1[c];
        }
    }
    __syncthreads();

    // ---- GEMM2: h @ w2 + b2, silu  (K=128) ----
    #pragma unroll
    for (int i = 0; i < 4; ++i)
        #pragma unroll
        for (int j = 0; j < 4; ++j) acc[i][j] = 0.f;
    {
        const float* wp = w2 + c0;
        #pragma unroll 8
        for (int k = 0; k < 128; ++k) {
            f32x4 wv = *(const f32x4*)(wp + k * 128);
            f32x4 xv = *(const f32x4*)(sXT + k * ROWS + rr);
            #pragma unroll
            for (int i = 0; i < 4; ++i)
                #pragma unroll
                for (int j = 0; j < 4; ++j)
                    acc[i][j] += xv[i] * wv[j];
        }
    }
    {
        f32x4 bv = *(const f32x4*)(b2 + c0);
        #pragma unroll
        for (int i = 0; i < 4; ++i)
            #pragma unroll
            for (int j = 0; j < 4; ++j) {
                float v = acc[i][j] + bv[j];
                v = v / (1.f + __expf(-v));       // silu
                sH[(rr + i) * HPAD + c0 + j] = v;
            }
    }
    __syncthreads();

    // ---- LN2 ----
    {
        const int row = t >> 3, j = t & 7;
        float vals[16];
        float s = 0.f, ss = 0.f;
        #pragma unroll
        for (int i = 0; i < 16; ++i) {
            float v = sH[row * HPAD + (i * 8 + j)];
            vals[i] = v; s += v; ss += v * v;
        }
        #pragma unroll
        for (int off = 1; off < 8; off <<= 1) {
            s  += __shfl_xor(s,  off);
            ss += __shfl_xor(ss, off);
        }
        float mu   = s * (1.f / 128.f);
        float var  = ss * (1.f / 128.f) - mu * mu;
        float rstd = rsqrtf(var + 1e-5f);
        #pragma unroll
        for (int i = 0; i < 16; ++i) {
            int c = i * 8 + j;
            sXT[c * ROWS + row] = (vals[i] - mu) * rstd * g2[c] + be2[c];
        }
    }
    __syncthreads();

    // ---- GEMM3: h @ w3 + b3  (K=128); write out columns [0,128) ----
    #pragma unroll
    for (int i = 0; i < 4; ++i)
        #pragma unroll
        for (int j = 0; j < 4; ++j) acc[i][j] = 0.f;
    {
        const float* wp = w3 + c0;
        #pragma unroll 8
        for (int k = 0; k < 128; ++k) {
            f32x4 wv = *(const f32x4*)(wp + k * 128);
            f32x4 xv = *(const f32x4*)(sXT + k * ROWS + rr);
            #pragma unroll
            for (int i = 0; i < 4; ++i)
                #pragma unroll
                for (int j = 0; j < 4; ++j)
                    acc[i][j] += xv[i] * wv[j];
        }
    }
    {
        f32x4 bv = *(const f32x4*)(b3 + c0);
        #pragma unroll
        for (int i = 0; i < 4; ++i) {
            f32x4 o;
            o.x = acc[i][0] + bv.x;
            o.y = acc[i][1] + bv.y;
            o.z = acc[i][2] + bv.z;
            o.w = acc[i][3] + bv.w;
            *(f32x4*)(out + (size_t)(r0 + rr + i) * DIM + c0) = o;
        }
    }
}

extern "C" void kernel_launch(void* const* d_in, const int* in_sizes, int n_in,
                              void* d_out, int out_size, void* d_ws, size_t ws_size,
                              hipStream_t stream) {
    const float* ten = (const float*)d_in[0];
    // d_in[1] = rep_layout (integer) — layout is compile-time known, unused
    const float* w1  = (const float*)d_in[2];
    const float* g1  = (const float*)d_in[3];
    const float* be1 = (const float*)d_in[4];
    const float* w2  = (const float*)d_in[5];
    const float* b2  = (const float*)d_in[6];
    const float* g2  = (const float*)d_in[7];
    const float* be2 = (const float*)d_in[8];
    const float* w3  = (const float*)d_in[9];
    const float* b3  = (const float*)d_in[10];
    float* out = (float*)d_out;

    dim3 grid(NROWS / ROWS);   // 3125
    dim3 block(BLK);
    evmlp_kernel<<<grid, block, 0, stream>>>(ten, w1, g1, be1, w2, b2, g2, be2, w3, b3, out);
}